// Round 5
// baseline (336.183 us; speedup 1.0000x reference)
//
#include <hip/hip_runtime.h>
#include <hip/hip_bf16.h>

// Complex 2x nearest-neighbor upsample, PLANAR output layout (verified R4):
//   out = (2, B, 2H, 2W, C) float32; plane 0 = real, plane 1 = imag
//   out[p][b][ho][wo][c] = x_{re,im}[b, ho/2, wo/2, c]
//
// One thread per (b, output row ho, input col wi, 4-channel group):
//   2 float4 loads (re, im) -- perfectly coalesced, zero intra-wave
//   redundancy (vertical 2x reuse across ho rows is served by L2/L3) --
//   then 4 plain float4 stores: horizontal duplicate pixels (2wi, 2wi+1)
//   in both planes. Stores are full 128B-line dense at wave level.
// NOTE: nontemporal stores removed (R4: 2.0 TB/s effective vs 6.4 TB/s
// achieved by the harness's plain-store fill on the same buffer).

#define BB 16
#define HH 128
#define WW 128
#define CC 64
#define OH (2 * HH)   // 256
#define OW (2 * WW)   // 256

typedef float vfloat4 __attribute__((ext_vector_type(4)));

__global__ __launch_bounds__(256) void complex_upsample2x_rows(
    const float* __restrict__ x_re,
    const float* __restrict__ x_im,
    float* __restrict__ out,
    unsigned plane_vec4,   // float4s per output plane = B*OH*OW*C/4
    int n_planes,
    unsigned total) {
    const unsigned q = blockIdx.x * blockDim.x + threadIdx.x;
    if (q >= total) return;

    const unsigned g  = q & (CC / 4 - 1);          // channel group: 4 floats
    const unsigned wi = (q >> 4) & (WW - 1);       // input column
    const unsigned ho = (q >> 11) & (OH - 1);      // output row
    const unsigned b  = q >> 19;                   // batch
    const unsigned hi = ho >> 1;

    // input float4 index
    const unsigned in_q = (((b * HH + hi) * WW) + wi) * (CC / 4) + g;
    // output float4 index of pixel (b, ho, 2*wi), channel group g
    const unsigned out_q = (((b * OH + ho) * OW) + 2 * wi) * (CC / 4) + g;

    const vfloat4 re = *(reinterpret_cast<const vfloat4*>(x_re) + in_q);
    vfloat4* outv = reinterpret_cast<vfloat4*>(out);
    outv[out_q]            = re;   // pixel 2*wi
    outv[out_q + CC / 4]   = re;   // pixel 2*wi + 1

    if (n_planes == 2) {
        const vfloat4 im = *(reinterpret_cast<const vfloat4*>(x_im) + in_q);
        outv[plane_vec4 + out_q]          = im;
        outv[plane_vec4 + out_q + CC / 4] = im;
    }
}

extern "C" void kernel_launch(void* const* d_in, const int* in_sizes, int n_in,
                              void* d_out, int out_size, void* d_ws, size_t ws_size,
                              hipStream_t stream) {
    const float* x_re = (const float*)d_in[0];
    const float* x_im = (const float*)d_in[1];
    float* out = (float*)d_out;

    const unsigned plane_elems = BB * OH * OW * CC;           // 67,108,864
    const int n_planes = (out_size >= (int64_t)2 * plane_elems) ? 2 : 1;
    const unsigned plane_vec4 = plane_elems / 4;              // 16,777,216

    const unsigned total = BB * OH * WW * (CC / 4);           // 8,388,608 threads
    const int block = 256;
    const unsigned grid = (total + block - 1) / block;        // 32,768 blocks
    complex_upsample2x_rows<<<grid, block, 0, stream>>>(x_re, x_im, out,
                                                        plane_vec4, n_planes, total);
}